// Round 12
// baseline (2730.677 us; speedup 1.0000x reference)
//
#include <hip/hip_runtime.h>

#define NSEQ 1028
#define TT   256
#define CC   64
#define HH   256
#define CH   32                 // recurrence chunk (xg recompute period)
#define SLABE 32768             // elems per kt slab: 8 waves * 8 ct * 512
// fused-kernel geometry (K=256)
#define XROW 528                // A row bytes: 256*2 + 16 pad
#define XG_A (16*XROW)          // 8448 per A buffer
#define LYS  1040               // y-stage stride/seq: 8t*128 + 16 pad (65*16 -> conflict-free)
#define XG_LDS (2*XG_A + 8192 + 2*SLABE*2)   // A0+A1 + y-extra + kt4,5 = 156160
// fallback geometry (K=320)
#define AROWB 656
#define FB_LDS (2*16*AROWB + 2*SLABE*2)      // 152064
#define OUTP_LDS (128*264*2 + 64*264*2)      // 101376

typedef unsigned short u16;
typedef float  f32x4 __attribute__((ext_vector_type(4)));
typedef __bf16 v8bf  __attribute__((ext_vector_type(8)));

__device__ __forceinline__ u16 f2bf(float f){
  unsigned u = __builtin_bit_cast(unsigned, f);
  u += 0x7FFFu + ((u >> 16) & 1u);
  return (u16)(u >> 16);
}
__device__ __forceinline__ float sigm(float x){
  float t = __builtin_amdgcn_exp2f(-1.4426950408889634f * x);
  return __builtin_amdgcn_rcpf(1.0f + t);
}
__device__ __forceinline__ float tanh_f(float x){
  float a = __builtin_fabsf(x);
  float t = __builtin_amdgcn_exp2f(-2.885390081777927f * a);
  float r = (1.0f - t) * __builtin_amdgcn_rcpf(1.0f + t);
  return __builtin_copysignf(r, x);
}
__device__ __forceinline__ void mfma_a(f32x4& d, v8bf a, v8bf b){
  asm("v_mfma_f32_16x16x32_bf16 %0, %1, %2, %0" : "+v"(d) : "v"(a), "a"(b));
}
__device__ __forceinline__ void mfma_v(f32x4& d, v8bf a, v8bf b){
  asm("v_mfma_f32_16x16x32_bf16 %0, %1, %2, %0" : "+v"(d) : "v"(a), "v"(b));
}
// barrier without vmcnt drain: LDS visibility only (globals stay in flight)
__device__ __forceinline__ void soft_barrier(){
  asm volatile("s_waitcnt lgkmcnt(0)" ::: "memory");
  __builtin_amdgcn_sched_barrier(0);
  __builtin_amdgcn_s_barrier();
  __builtin_amdgcn_sched_barrier(0);
}
// full drain barrier (global stores visible after): once per chunk
__device__ __forceinline__ void drain_barrier(){
  asm volatile("s_waitcnt vmcnt(0) lgkmcnt(0)" ::: "memory");
  __builtin_amdgcn_sched_barrier(0);
  __builtin_amdgcn_s_barrier();
  __builtin_amdgcn_sched_barrier(0);
}

// ---- pack W = [W_hh | W_ih] into per-(kt,wave,ct) MFMA B-frags, bf16
__global__ void k_pack_w(const float* __restrict__ Whh, const float* __restrict__ Wih,
                         u16* __restrict__ wpack){
  int idx = blockIdx.x*256 + threadIdx.x;
  if (idx >= 10*SLABE) return;                 // 327680
  int j    = idx & 7;
  int lane = (idx >> 3) & 63;
  int ct   = (idx >> 9) & 7;
  int w    = (idx >> 12) & 7;
  int kt   = idx >> 15;
  int col  = (ct >> 1)*256 + w*32 + (ct & 1)*16 + (lane & 15);
  int k    = kt*32 + (lane >> 4)*8 + j;
  float v  = (k < 256) ? Whh[col*256 + k] : Wih[col*64 + (k - 256)];
  wpack[idx] = f2bf(v);
}

__global__ void k_bias(const float* __restrict__ bi, const float* __restrict__ bh,
                       float* __restrict__ bias){
  int i = blockIdx.x*256 + threadIdx.x;
  if (i < 1024) bias[i] = bi[i] + bh[i];
}

__global__ void k_wlin(const float* __restrict__ Wl, u16* __restrict__ wlin){
  int i = blockIdx.x*256 + threadIdx.x;
  if (i >= 64*264) return;
  int col = i / 264, k = i % 264;
  wlin[i] = (k < 256) ? f2bf(Wl[col*256 + k]) : (u16)0;
}

// ---- x(B,C,F,T) -> y(n,t,c) bf16, n = b*257+f
__global__ void k_ytrans(const float* __restrict__ x, u16* __restrict__ ybuf){
  __shared__ u16 tile[64][257];
  int n = blockIdx.x, b = n / 257, f = n % 257, tid = threadIdx.x;
  for (int i = tid; i < 64*256; i += 256){
    int c = i >> 8, t = i & 255;
    tile[c][t] = f2bf(x[((size_t)(b*64 + c)*257 + f)*256 + t]);
  }
  __syncthreads();
  for (int i = tid; i < 256*64; i += 256){
    int t = i >> 6, c = i & 63;
    ybuf[((size_t)n*256 + t)*64 + c] = tile[c][t];
  }
}

// ---- fused persistent LSTM: 65 blocks x 512 thr. Per 32-step chunk:
//  phase 1 (xg): xg = y@W_ih^T + bias via MFMA, stored bf16 to block-private xgb
//  phase 2 (recurrence): K=256; kt0..3 AGPR, kt4,5 LDS, kt6,7 streamed; acc init
//  from prefetched xg fragment. creg persists in registers across chunks.
__global__ __launch_bounds__(512, 2) void k_lstm_f(const u16* __restrict__ wpack,
      const float* __restrict__ bias, const u16* __restrict__ ybuf,
      u16* __restrict__ xgb, u16* __restrict__ hbuf){
  extern __shared__ char smem[];
  char* lA = smem;                              // [2][16][XROW]
  char* lY = smem + XG_A;                       // y-stage: A1 + 8KB extra = 16640B
  u16*  lW = (u16*)(smem + 2*XG_A + 8192);      // kt4,5 slabs
  const int tid = threadIdx.x, lane = tid & 63, w = tid >> 6;
  const int g = blockIdx.x, n0 = g*16;
  const int l15 = lane & 15, q = lane >> 4;
  const int srow = tid >> 5, schunk = tid & 31;
  // y-stage roles: 1024 uint4 over 512 thr x2
  const int yc8 = tid & 7, yt3 = (tid >> 3) & 7, yseq0 = tid >> 6, yseq1 = (tid >> 6) + 8;

  v8bf wreg[4][8];                              // kt0..3 -> AGPR via "a" uses
  #pragma unroll
  for (int kt = 0; kt < 4; ++kt)
    #pragma unroll
    for (int ct = 0; ct < 8; ++ct)
      wreg[kt][ct] = *(const v8bf*)(wpack + ((kt*8 + w)*8 + ct)*512 + lane*8);
  { // LDS-resident kt4,5
    const uint4* src = (const uint4*)(wpack + 4*SLABE);
    uint4* dst = (uint4*)lW;
    for (int i = tid; i < (2*SLABE)/8; i += 512) dst[i] = src[i];
  }
  float biasr[8];
  #pragma unroll
  for (int ct = 0; ct < 8; ++ct)
    biasr[ct] = bias[(ct >> 1)*256 + w*32 + (ct & 1)*16 + l15];
  { // zero A0 (h(-1)=0)
    unsigned* z = (unsigned*)lA;
    for (int i = tid; i < XG_A/4; i += 512) z[i] = 0;
  }
  f32x4 creg[2];
  creg[0] = (f32x4){0.f,0.f,0.f,0.f};
  creg[1] = (f32x4){0.f,0.f,0.f,0.f};
  __syncthreads();

  const u16* wp = wpack;                        // opaque-refreshed (defeats LICM)
  u16* xgblk = xgb + (size_t)g * (CH*16384);    // block-private chunk slab (1MB)

  for (int t0 = 0; t0 < TT; t0 += CH){
    // ================= phase 1: xg for [t0, t0+CH) =================
    {
      v8bf wf0[8], wf1[8];                      // kt8,9 frags, held per chunk
      #pragma unroll
      for (int ct = 0; ct < 8; ++ct){
        wf0[ct] = *(const v8bf*)(wpack + ((8*8 + w)*8 + ct)*512 + lane*8);
        wf1[ct] = *(const v8bf*)(wpack + ((9*8 + w)*8 + ct)*512 + lane*8);
      }
      for (int tb = 0; tb < CH; tb += 8){
        uint4 v0 = {0,0,0,0}, v1 = {0,0,0,0};
        if (n0 + yseq0 < NSEQ)
          v0 = *(const uint4*)(ybuf + ((size_t)(n0+yseq0)*TT + t0+tb+yt3)*64 + yc8*8);
        if (n0 + yseq1 < NSEQ)
          v1 = *(const uint4*)(ybuf + ((size_t)(n0+yseq1)*TT + t0+tb+yt3)*64 + yc8*8);
        soft_barrier();                         // prior group's lY reads done
        *(uint4*)(lY + yseq0*LYS + yt3*128 + yc8*16) = v0;
        *(uint4*)(lY + yseq1*LYS + yt3*128 + yc8*16) = v1;
        soft_barrier();                         // lY visible
        #pragma unroll
        for (int tt = 0; tt < 8; ++tt){
          v8bf a0 = *(const v8bf*)(lY + l15*LYS + tt*128 + q*16);
          v8bf a1 = *(const v8bf*)(lY + l15*LYS + tt*128 + 64 + q*16);
          u16* dst = xgblk + ((((size_t)(tb+tt))*8 + w)*64 + lane)*32;
          { // ct 0..3
            f32x4 xa[4];
            #pragma unroll
            for (int c = 0; c < 4; ++c){
              xa[c] = (f32x4){biasr[c], biasr[c], biasr[c], biasr[c]};
              xa[c] = __builtin_amdgcn_mfma_f32_16x16x32_bf16(a0, wf0[c], xa[c], 0,0,0);
              xa[c] = __builtin_amdgcn_mfma_f32_16x16x32_bf16(a1, wf1[c], xa[c], 0,0,0);
            }
            unsigned d[8];
            #pragma unroll
            for (int c = 0; c < 4; ++c){
              d[c*2]   = (unsigned)f2bf(xa[c][0]) | ((unsigned)f2bf(xa[c][1]) << 16);
              d[c*2+1] = (unsigned)f2bf(xa[c][2]) | ((unsigned)f2bf(xa[c][3]) << 16);
            }
            *(uint4*)(dst)     = (uint4){d[0], d[1], d[2], d[3]};
            *(uint4*)(dst + 8) = (uint4){d[4], d[5], d[6], d[7]};
          }
          { // ct 4..7
            f32x4 xa[4];
            #pragma unroll
            for (int c = 0; c < 4; ++c){
              xa[c] = (f32x4){biasr[c+4], biasr[c+4], biasr[c+4], biasr[c+4]};
              xa[c] = __builtin_amdgcn_mfma_f32_16x16x32_bf16(a0, wf0[c+4], xa[c], 0,0,0);
              xa[c] = __builtin_amdgcn_mfma_f32_16x16x32_bf16(a1, wf1[c+4], xa[c], 0,0,0);
            }
            unsigned d[8];
            #pragma unroll
            for (int c = 0; c < 4; ++c){
              d[c*2]   = (unsigned)f2bf(xa[c][0]) | ((unsigned)f2bf(xa[c][1]) << 16);
              d[c*2+1] = (unsigned)f2bf(xa[c][2]) | ((unsigned)f2bf(xa[c][3]) << 16);
            }
            *(uint4*)(dst + 16) = (uint4){d[0], d[1], d[2], d[3]};
            *(uint4*)(dst + 24) = (uint4){d[4], d[5], d[6], d[7]};
          }
        }
      }
    }
    drain_barrier();                            // xg stores visible for read-back

    // ================= phase 2: recurrence [t0, t0+CH) =================
    asm("" : "+s"(wp));
    v8bf sbuf[8];
    uint4 xgv[4];
    { // chunk prologue: kt6 + xg(t0)
      const u16* wpw0 = wp + w*4096 + lane*8;
      #pragma unroll
      for (int ct = 0; ct < 8; ++ct) sbuf[ct] = *(const v8bf*)(wpw0 + 6*SLABE + ct*512);
      const u16* xb = xgblk + ((0*8 + w)*64 + lane)*32;
      xgv[0] = *(const uint4*)(xb +  0);
      xgv[1] = *(const uint4*)(xb +  8);
      xgv[2] = *(const uint4*)(xb + 16);
      xgv[3] = *(const uint4*)(xb + 24);
    }

    for (int tl = 0; tl < CH; ++tl){
      const int t = t0 + tl;
      char* Acur = lA + (t & 1)*XG_A;
      char* Anxt = lA + ((t + 1) & 1)*XG_A;
      asm("" : "+s"(wp));
      const u16* wpw = wp + w*4096 + lane*8;

      // h(t-1) writeout (overlaps MFMA)
      if (t >= 1 && n0 + srow < NSEQ){
        uint4 hv = *(const uint4*)(Acur + srow*XROW + schunk*16);
        *(uint4*)(hbuf + ((size_t)(n0 + srow)*TT + (t - 1))*HH + schunk*8) = hv;
      }

      // acc init from xg fragment (bf16 -> f32 by shift)
      f32x4 acc[8];
      #pragma unroll
      for (int ct = 0; ct < 8; ++ct){
        #pragma unroll
        for (int p = 0; p < 2; ++p){
          unsigned u = ((const unsigned*)&xgv[(ct*2 + p) >> 2])[(ct*2 + p) & 3];
          acc[ct][2*p]     = __builtin_bit_cast(float, u << 16);
          acc[ct][2*p + 1] = __builtin_bit_cast(float, u & 0xffff0000u);
        }
      }
      asm volatile("s_nop 1"
        : "+v"(acc[0]), "+v"(acc[1]), "+v"(acc[2]), "+v"(acc[3]),
          "+v"(acc[4]), "+v"(acc[5]), "+v"(acc[6]), "+v"(acc[7]));

      // prefetch xg(t+1) (in flight across the whole step)
      if (tl + 1 < CH){
        const u16* xb = xgblk + ((((size_t)(tl + 1))*8 + w)*64 + lane)*32;
        xgv[0] = *(const uint4*)(xb +  0);
        xgv[1] = *(const uint4*)(xb +  8);
        xgv[2] = *(const uint4*)(xb + 16);
        xgv[3] = *(const uint4*)(xb + 24);
      }
      __builtin_amdgcn_sched_barrier(0);

      #define AFX(kt) (*(const v8bf*)(Acur + l15*XROW + (kt)*64 + q*16))
      #define LFX(kt,ct) (*(const v8bf*)(lW + (((kt)-4)*8 + w)*4096 + (ct)*512 + lane*8))

      { v8bf a = AFX(6);                        // kt6 (prefetched) -> refill kt7
        #pragma unroll
        for (int ct = 0; ct < 8; ++ct) mfma_v(acc[ct], a, sbuf[ct]);
        #pragma unroll
        for (int ct = 0; ct < 8; ++ct) sbuf[ct] = *(const v8bf*)(wpw + 7*SLABE + ct*512);
        __builtin_amdgcn_sched_barrier(0); }
      { v8bf a = AFX(0);                        // kt0..3 (AGPR)
        #pragma unroll
        for (int ct = 0; ct < 8; ++ct) mfma_a(acc[ct], a, wreg[0][ct]); }
      { v8bf a = AFX(1);
        #pragma unroll
        for (int ct = 0; ct < 8; ++ct) mfma_a(acc[ct], a, wreg[1][ct]); }
      { v8bf a = AFX(2);
        #pragma unroll
        for (int ct = 0; ct < 8; ++ct) mfma_a(acc[ct], a, wreg[2][ct]); }
      { v8bf a = AFX(3);
        #pragma unroll
        for (int ct = 0; ct < 8; ++ct) mfma_a(acc[ct], a, wreg[3][ct]); }
      { v8bf a = AFX(4);                        // kt4 (LDS)
        #pragma unroll
        for (int ct = 0; ct < 8; ++ct) mfma_v(acc[ct], a, LFX(4,ct)); }
      { v8bf a = AFX(5);                        // kt5 (LDS)
        #pragma unroll
        for (int ct = 0; ct < 8; ++ct) mfma_v(acc[ct], a, LFX(5,ct)); }
      { v8bf a = AFX(7);                        // kt7 -> refill kt6 for t+1
        #pragma unroll
        for (int ct = 0; ct < 8; ++ct) mfma_v(acc[ct], a, sbuf[ct]);
        #pragma unroll
        for (int ct = 0; ct < 8; ++ct) sbuf[ct] = *(const v8bf*)(wpw + 6*SLABE + ct*512);
        __builtin_amdgcn_sched_barrier(0); }

      asm volatile("s_nop 7\n\ts_nop 7\n\ts_nop 7"
        : "+v"(acc[0]), "+v"(acc[1]), "+v"(acc[2]), "+v"(acc[3]),
          "+v"(acc[4]), "+v"(acc[5]), "+v"(acc[6]), "+v"(acc[7]));

      // cell: lane owns units w*32+u*16+l15, rows 4q+j
      #pragma unroll
      for (int u = 0; u < 2; ++u){
        #pragma unroll
        for (int j = 0; j < 4; ++j){
          float xi = acc[0 + u][j], xf = acc[2 + u][j], xg = acc[4 + u][j], xo = acc[6 + u][j];
          float cv = sigm(xf)*creg[u][j] + sigm(xi)*tanh_f(xg);
          float hv = sigm(xo)*tanh_f(cv);
          creg[u][j] = cv;
          int row = 4*q + j, unit = w*32 + u*16 + l15;
          *(u16*)(Anxt + row*XROW + unit*2) = f2bf(hv);
        }
      }
      soft_barrier();
    }
  }
  { // final h(255) writeout from A0
    char* Afin = lA + (TT & 1)*XG_A;
    if (n0 + srow < NSEQ){
      uint4 hv = *(const uint4*)(Afin + srow*XROW + schunk*16);
      *(uint4*)(hbuf + ((size_t)(n0 + srow)*TT + (TT - 1))*HH + schunk*8) = hv;
    }
  }
}

// ---- fallback LSTM (r10 verbatim, proven ~1120 us) for small ws
__global__ __launch_bounds__(512, 2) void k_lstm_fb(const u16* __restrict__ wpack,
      const float* __restrict__ bias, const u16* __restrict__ ybuf,
      u16* __restrict__ hbuf){
  extern __shared__ char smem[];
  char* lA = smem;
  u16*  lW = (u16*)(smem + 2*16*AROWB);
  const int tid = threadIdx.x, lane = tid & 63, w = tid >> 6;
  const int n0 = blockIdx.x * 16;
  const int l15 = lane & 15, q = lane >> 4;
  const int srow = tid >> 5, schunk = tid & 31;

  v8bf wreg[4][8];
  #pragma unroll
  for (int kt = 0; kt < 4; ++kt)
    #pragma unroll
    for (int ct = 0; ct < 8; ++ct)
      wreg[kt][ct] = *(const v8bf*)(wpack + ((kt*8 + w)*8 + ct)*512 + lane*8);
  {
    const uint4* src = (const uint4*)(wpack + 4*SLABE);
    uint4* dst = (uint4*)lW;
    for (int i = tid; i < (2*SLABE)/8; i += 512) dst[i] = src[i];
  }
  float biasr[8];
  #pragma unroll
  for (int ct = 0; ct < 8; ++ct)
    biasr[ct] = bias[(ct >> 1)*256 + w*32 + (ct & 1)*16 + l15];
  {
    unsigned* z = (unsigned*)lA;
    for (int i = tid; i < (2*16*AROWB)/4; i += 512) z[i] = 0;
  }
  __syncthreads();
  {
    unsigned v = 0;
    if (n0 + srow < NSEQ)
      v = *(const unsigned*)(ybuf + ((size_t)(n0 + srow)*TT + 0)*64 + schunk*2);
    *(unsigned*)(lA + srow*AROWB + 512 + schunk*4) = v;
  }
  f32x4 creg[2];
  creg[0] = (f32x4){0.f,0.f,0.f,0.f};
  creg[1] = (f32x4){0.f,0.f,0.f,0.f};
  __syncthreads();

  const u16* wp = wpack;
  v8bf sbuf[8];
  {
    const u16* wpw0 = wp + w*4096 + lane*8;
    #pragma unroll
    for (int ct = 0; ct < 8; ++ct) sbuf[ct] = *(const v8bf*)(wpw0 + 6*SLABE + ct*512);
  }

  for (int t = 0; t < TT; ++t){
    char* Acur = lA + (t & 1)*16*AROWB;
    char* Anxt = lA + ((t + 1) & 1)*16*AROWB;
    asm("" : "+s"(wp));
    const u16* wpw = wp + w*4096 + lane*8;

    unsigned yv = 0;
    if (t + 1 < TT && n0 + srow < NSEQ)
      yv = *(const unsigned*)(ybuf + ((size_t)(n0 + srow)*TT + (t + 1))*64 + schunk*2);

    if (t >= 1 && n0 + srow < NSEQ){
      uint4 hv = *(const uint4*)(Acur + srow*AROWB + schunk*16);
      *(uint4*)(hbuf + ((size_t)(n0 + srow)*TT + (t - 1))*HH + schunk*8) = hv;
    }

    f32x4 acc[8];
    #pragma unroll
    for (int ct = 0; ct < 8; ++ct)
      acc[ct] = (f32x4){biasr[ct], biasr[ct], biasr[ct], biasr[ct]};
    asm volatile("s_nop 1"
      : "+v"(acc[0]), "+v"(acc[1]), "+v"(acc[2]), "+v"(acc[3]),
        "+v"(acc[4]), "+v"(acc[5]), "+v"(acc[6]), "+v"(acc[7]));

    #define AFRAG(kt) (*(const v8bf*)(Acur + l15*AROWB + (kt)*64 + q*16))
    #define LFRAG(kt,ct) (*(const v8bf*)(lW + (((kt)-4)*8 + w)*4096 + (ct)*512 + lane*8))

    { v8bf a = AFRAG(0);
      #pragma unroll
      for (int ct = 0; ct < 8; ++ct) mfma_a(acc[ct], a, wreg[0][ct]); }
    { v8bf a = AFRAG(1);
      #pragma unroll
      for (int ct = 0; ct < 8; ++ct) mfma_a(acc[ct], a, wreg[1][ct]); }
    { v8bf a = AFRAG(6);
      #pragma unroll
      for (int ct = 0; ct < 8; ++ct) mfma_v(acc[ct], a, sbuf[ct]);
      #pragma unroll
      for (int ct = 0; ct < 8; ++ct) sbuf[ct] = *(const v8bf*)(wpw + 7*SLABE + ct*512);
      __builtin_amdgcn_sched_barrier(0); }
    { v8bf a = AFRAG(2);
      #pragma unroll
      for (int ct = 0; ct < 8; ++ct) mfma_a(acc[ct], a, wreg[2][ct]); }
    { v8bf a = AFRAG(3);
      #pragma unroll
      for (int ct = 0; ct < 8; ++ct) mfma_a(acc[ct], a, wreg[3][ct]); }
    { v8bf a = AFRAG(7);
      #pragma unroll
      for (int ct = 0; ct < 8; ++ct) mfma_v(acc[ct], a, sbuf[ct]);
      #pragma unroll
      for (int ct = 0; ct < 8; ++ct) sbuf[ct] = *(const v8bf*)(wpw + 8*SLABE + ct*512);
      __builtin_amdgcn_sched_barrier(0); }
    { v8bf a = AFRAG(4);
      #pragma unroll
      for (int ct = 0; ct < 8; ++ct) mfma_v(acc[ct], a, LFRAG(4,ct)); }
    { v8bf a = AFRAG(8);
      #pragma unroll
      for (int ct = 0; ct < 8; ++ct) mfma_v(acc[ct], a, sbuf[ct]);
      #pragma unroll
      for (int ct = 0; ct < 8; ++ct) sbuf[ct] = *(const v8bf*)(wpw + 9*SLABE + ct*512);
      __builtin_amdgcn_sched_barrier(0); }
    { v8bf a = AFRAG(5);
      #pragma unroll
      for (int ct = 0; ct < 8; ++ct) mfma_v(acc[ct], a, LFRAG(5,ct)); }
    { v8bf a = AFRAG(9);
      #pragma unroll
      for (int ct = 0; ct < 8; ++ct) mfma_v(acc[ct], a, sbuf[ct]);
      #pragma unroll
      for (int ct = 0; ct < 8; ++ct) sbuf[ct] = *(const v8bf*)(wpw + 6*SLABE + ct*512);
      __builtin_amdgcn_sched_barrier(0); }

    asm volatile("s_nop 7\n\ts_nop 7\n\ts_nop 7"
      : "+v"(acc[0]), "+v"(acc[1]), "+v"(acc[2]), "+v"(acc[3]),
        "+v"(acc[4]), "+v"(acc[5]), "+v"(acc[6]), "+v"(acc[7]));

    #pragma unroll
    for (int u = 0; u < 2; ++u){
      #pragma unroll
      for (int j = 0; j < 4; ++j){
        float xi = acc[0 + u][j], xf = acc[2 + u][j], xg = acc[4 + u][j], xo = acc[6 + u][j];
        float cv = sigm(xf)*creg[u][j] + sigm(xi)*tanh_f(xg);
        float hv = sigm(xo)*tanh_f(cv);
        creg[u][j] = cv;
        int row = 4*q + j, unit = w*32 + u*16 + l15;
        *(u16*)(Anxt + row*AROWB + unit*2) = f2bf(hv);
      }
    }
    if (t + 1 < TT)
      *(unsigned*)(Anxt + srow*AROWB + 512 + schunk*4) = yv;
    soft_barrier();
  }
  {
    char* Afin = lA + (TT & 1)*16*AROWB;
    if (n0 + srow < NSEQ){
      uint4 hv = *(const uint4*)(Afin + srow*AROWB + schunk*16);
      *(uint4*)(hbuf + ((size_t)(n0 + srow)*TT + (TT - 1))*HH + schunk*8) = hv;
    }
  }
}

// ---- out = h @ W_lin^T + b_lin, written as (B,OUT,F,T)
__global__ __launch_bounds__(256) void k_outproj(const u16* __restrict__ hbuf,
      const u16* __restrict__ wlin, const float* __restrict__ blin,
      float* __restrict__ out){
  extern __shared__ char smem[];
  u16* sA = (u16*)smem;
  u16* sB = (u16*)(smem + 128*264*2);
  const int n = blockIdx.x, th = blockIdx.y, t0 = th*128;
  const int b = n / 257, f = n % 257;
  const int tid = threadIdx.x, lane = tid & 63, wv = tid >> 6;

  for (int i = tid; i < 128*32; i += 256){
    int r = i >> 5, part = i & 31;
    *(uint4*)(sA + r*264 + part*8) =
        *(const uint4*)(hbuf + ((size_t)n*TT + t0 + r)*HH + part*8);
  }
  for (int i = tid; i < (64*264)/2; i += 256)
    ((unsigned*)sB)[i] = ((const unsigned*)wlin)[i];
  __syncthreads();

  f32x4 acc[2][4];
  #pragma unroll
  for (int m = 0; m < 2; ++m)
    #pragma unroll
    for (int nt = 0; nt < 4; ++nt){
      float bv = blin[nt*16 + (lane & 15)];
      acc[m][nt] = (f32x4){bv, bv, bv, bv};
    }
  const int khi = (lane >> 4) * 8;
  #pragma unroll
  for (int kt = 0; kt < 8; ++kt){
    v8bf av[2];
    #pragma unroll
    for (int m = 0; m < 2; ++m){
      int mt = wv*2 + m;
      av[m] = *(const v8bf*)(sA + (mt*16 + (lane & 15))*264 + kt*32 + khi);
    }
    #pragma unroll
    for (int nt = 0; nt < 4; ++nt){
      v8bf bv = *(const v8bf*)(sB + (nt*16 + (lane & 15))*264 + kt*32 + khi);
      #pragma unroll
      for (int m = 0; m < 2; ++m)
        acc[m][nt] = __builtin_amdgcn_mfma_f32_16x16x32_bf16(av[m], bv, acc[m][nt], 0, 0, 0);
    }
  }
  #pragma unroll
  for (int m = 0; m < 2; ++m){
    int mt = wv*2 + m;
    #pragma unroll
    for (int nt = 0; nt < 4; ++nt){
      int o = nt*16 + (lane & 15);
      int tb = t0 + mt*16 + 4*(lane >> 4);
      *(f32x4*)(out + (((size_t)b*64 + o)*257 + f)*TT + tb) = acc[m][nt];
    }
  }
}

extern "C" void kernel_launch(void* const* d_in, const int* in_sizes, int n_in,
                              void* d_out, int out_size, void* d_ws, size_t ws_size,
                              hipStream_t stream) {
  const float* x   = (const float*)d_in[0];
  const float* Wih = (const float*)d_in[1];
  const float* Whh = (const float*)d_in[2];
  const float* bih = (const float*)d_in[3];
  const float* bhh = (const float*)d_in[4];
  const float* Wl  = (const float*)d_in[5];
  const float* bl  = (const float*)d_in[6];
  float* out = (float*)d_out;

  char* p = (char*)d_ws;
  u16*   wpack = (u16*)p;   p += 655360;
  float* bias  = (float*)p; p += 4096;
  u16*   wlin  = (u16*)p;   p += 33792;
  u16*   ybuf  = (u16*)p;   p += (size_t)NSEQ*TT*CC*2;   // 33,685,504
  u16*   hbuf  = (u16*)p;   p += (size_t)NSEQ*TT*HH*2;   // 134,742,016
  u16*   xgb   = (u16*)p;
  const size_t NEED = (size_t)(p - (char*)d_ws) + 65ull*CH*16384*2;  // 237,278,208

  hipFuncSetAttribute((const void*)k_lstm_f,  hipFuncAttributeMaxDynamicSharedMemorySize, XG_LDS);
  hipFuncSetAttribute((const void*)k_lstm_fb, hipFuncAttributeMaxDynamicSharedMemorySize, FB_LDS);
  hipFuncSetAttribute((const void*)k_outproj, hipFuncAttributeMaxDynamicSharedMemorySize, OUTP_LDS);

  k_pack_w <<<1280, 256, 0, stream>>>(Whh, Wih, wpack);
  k_bias   <<<4,    256, 0, stream>>>(bih, bhh, bias);
  k_wlin   <<<66,   256, 0, stream>>>(Wl, wlin);
  k_ytrans <<<1028, 256, 0, stream>>>(x, ybuf);

  if (ws_size >= NEED)
    k_lstm_f <<<65, 512, XG_LDS, stream>>>(wpack, bias, ybuf, xgb, hbuf);
  else
    k_lstm_fb<<<65, 512, FB_LDS, stream>>>(wpack, bias, ybuf, hbuf);

  k_outproj<<<dim3(1028, 2), 256, OUTP_LDS, stream>>>(hbuf, wlin, bl, out);
}

// Round 14
// 1243.173 us; speedup vs baseline: 2.1965x; 2.1965x over previous
//
#include <hip/hip_runtime.h>

#define NSEQ 1028
#define TT   256
#define CC   64
#define HH   256
#define AROWB 656             // bytes per A row: 320*2 + 16 pad
#define SLABE 32768           // elems per kt slab: 8 waves * 8 ct * 512
#define LSTM_LDS (2*16*AROWB + 2*SLABE*2 + 4096)   // A dbuf + kt4,5 + bias = 156160
#define OUTP_LDS (128*264*2 + 64*264*2)            // 101376

typedef unsigned short u16;
typedef float  f32x4 __attribute__((ext_vector_type(4)));
typedef __bf16 v8bf  __attribute__((ext_vector_type(8)));

__device__ __forceinline__ u16 f2bf(float f){
  unsigned u = __builtin_bit_cast(unsigned, f);
  u += 0x7FFFu + ((u >> 16) & 1u);
  return (u16)(u >> 16);
}
__device__ __forceinline__ float sigm(float x){
  float t = __builtin_amdgcn_exp2f(-1.4426950408889634f * x);
  return __builtin_amdgcn_rcpf(1.0f + t);
}
__device__ __forceinline__ float tanh_f(float x){
  float a = __builtin_fabsf(x);
  float t = __builtin_amdgcn_exp2f(-2.885390081777927f * a);
  float r = (1.0f - t) * __builtin_amdgcn_rcpf(1.0f + t);
  return __builtin_copysignf(r, x);
}
__device__ __forceinline__ void mfma_a(f32x4& d, v8bf a, v8bf b){
  asm("v_mfma_f32_16x16x32_bf16 %0, %1, %2, %0" : "+v"(d) : "v"(a), "a"(b));
}
__device__ __forceinline__ void mfma_v(f32x4& d, v8bf a, v8bf b){
  asm("v_mfma_f32_16x16x32_bf16 %0, %1, %2, %0" : "+v"(d) : "v"(a), "v"(b));
}
// barrier without vmcnt drain: LDS visibility only (globals stay in flight)
__device__ __forceinline__ void soft_barrier(){
  asm volatile("s_waitcnt lgkmcnt(0)" ::: "memory");
  __builtin_amdgcn_sched_barrier(0);
  __builtin_amdgcn_s_barrier();
  __builtin_amdgcn_sched_barrier(0);
}

// ---- pack W = [W_hh | W_ih] into per-(kt,wave,ct) MFMA B-frags, bf16
__global__ void k_pack_w(const float* __restrict__ Whh, const float* __restrict__ Wih,
                         u16* __restrict__ wpack){
  int idx = blockIdx.x*256 + threadIdx.x;
  if (idx >= 10*SLABE) return;                 // 327680
  int j    = idx & 7;
  int lane = (idx >> 3) & 63;
  int ct   = (idx >> 9) & 7;
  int w    = (idx >> 12) & 7;
  int kt   = idx >> 15;
  int col  = (ct >> 1)*256 + w*32 + (ct & 1)*16 + (lane & 15);
  int k    = kt*32 + (lane >> 4)*8 + j;
  float v  = (k < 256) ? Whh[col*256 + k] : Wih[col*64 + (k - 256)];
  wpack[idx] = f2bf(v);
}

__global__ void k_bias(const float* __restrict__ bi, const float* __restrict__ bh,
                       float* __restrict__ bias){
  int i = blockIdx.x*256 + threadIdx.x;
  if (i < 1024) bias[i] = bi[i] + bh[i];
}

__global__ void k_wlin(const float* __restrict__ Wl, u16* __restrict__ wlin){
  int i = blockIdx.x*256 + threadIdx.x;
  if (i >= 64*264) return;
  int col = i / 264, k = i % 264;
  wlin[i] = (k < 256) ? f2bf(Wl[col*256 + k]) : (u16)0;
}

// ---- x(B,C,F,T) -> y(n,t,c) bf16, n = b*257+f
__global__ void k_ytrans(const float* __restrict__ x, u16* __restrict__ ybuf){
  __shared__ u16 tile[64][257];
  int n = blockIdx.x, b = n / 257, f = n % 257, tid = threadIdx.x;
  for (int i = tid; i < 64*256; i += 256){
    int c = i >> 8, t = i & 255;
    tile[c][t] = f2bf(x[((size_t)(b*64 + c)*257 + f)*256 + t]);
  }
  __syncthreads();
  for (int i = tid; i < 256*64; i += 256){
    int t = i >> 6, c = i & 63;
    ybuf[((size_t)n*256 + t)*64 + c] = tile[c][t];
  }
}

// ---- persistent LSTM: 65 blocks x 512 thr (8 waves), 16 seqs/block.
// Residency: kt0..3 AGPR (128/wave), kt4,5 LDS (128 KB), kt6..9 streamed from L2
// via TWO rolling register buffers (sbufA/sbufB): kt6,kt7 loaded a full step
// ahead; kt8/kt9 issued early enough that every consume has >=900cyc slack.
// bias lives in LDS (frees 8 VGPRs for the 2nd buffer). Soft barrier per step.
__global__ __launch_bounds__(512, 2) void k_lstm(const u16* __restrict__ wpack,
      const float* __restrict__ bias, const u16* __restrict__ ybuf,
      u16* __restrict__ hbuf){
  extern __shared__ char smem[];
  char*  lA = smem;                               // [2][16 rows][AROWB]
  u16*   lW = (u16*)(smem + 2*16*AROWB);          // kt4,5 slabs
  float* lB = (float*)(smem + 2*16*AROWB + 2*SLABE*2);  // bias[1024]
  const int tid = threadIdx.x, lane = tid & 63, w = tid >> 6;   // w 0..7
  const int n0 = blockIdx.x * 16;
  const int l15 = lane & 15, q = lane >> 4;
  const int srow = tid >> 5, schunk = tid & 31;   // staging roles

  // AGPR-resident W (kt0..3): 128 AGPR/wave, pinned by "a"-constrained uses
  v8bf wreg[4][8];
  #pragma unroll
  for (int kt = 0; kt < 4; ++kt)
    #pragma unroll
    for (int ct = 0; ct < 8; ++ct)
      wreg[kt][ct] = *(const v8bf*)(wpack + ((kt*8 + w)*8 + ct)*512 + lane*8);

  { // LDS-resident W (kt4,5)
    const uint4* src = (const uint4*)(wpack + 4*SLABE);
    uint4* dst = (uint4*)lW;
    for (int i = tid; i < (2*SLABE)/8; i += 512) dst[i] = src[i];
  }
  { // bias -> LDS
    for (int i = tid; i < 1024; i += 512) lB[i] = bias[i];
  }
  { // zero both A buffers (h(-1)=0)
    unsigned* z = (unsigned*)lA;
    for (int i = tid; i < (2*16*AROWB)/4; i += 512) z[i] = 0;
  }
  __syncthreads();
  { // stage y[t=0] into buf0
    unsigned v = 0;
    if (n0 + srow < NSEQ)
      v = *(const unsigned*)(ybuf + ((size_t)(n0 + srow)*TT + 0)*64 + schunk*2);
    *(unsigned*)(lA + srow*AROWB + 512 + schunk*4) = v;
  }
  f32x4 creg[2];
  creg[0] = (f32x4){0.f,0.f,0.f,0.f};
  creg[1] = (f32x4){0.f,0.f,0.f,0.f};
  __syncthreads();

  const u16* wp = wpack;           // opaque-refreshed each step (defeats LICM/CSE)

  // prologue: kt6 -> sbufA, kt7 -> sbufB (full-step slack before first consume)
  v8bf sA[8], sB[8];
  {
    const u16* wpw0 = wp + w*4096 + lane*8;
    #pragma unroll
    for (int ct = 0; ct < 8; ++ct) sA[ct] = *(const v8bf*)(wpw0 + 6*SLABE + ct*512);
    #pragma unroll
    for (int ct = 0; ct < 8; ++ct) sB[ct] = *(const v8bf*)(wpw0 + 7*SLABE + ct*512);
  }

  for (int t = 0; t < TT; ++t){
    char* Acur = lA + (t & 1)*16*AROWB;
    char* Anxt = lA + ((t + 1) & 1)*16*AROWB;

    asm("" : "+s"(wp));            // fresh base each iteration
    const u16* wpw = wp + w*4096 + lane*8;

    // y prefetch for t+1 (consumed at staging, pre-barrier)
    unsigned yv = 0;
    if (t + 1 < TT && n0 + srow < NSEQ)
      yv = *(const unsigned*)(ybuf + ((size_t)(n0 + srow)*TT + (t + 1))*64 + schunk*2);

    // h(t-1) writeout (fire-and-forget; no in-kernel reader)
    if (t >= 1 && n0 + srow < NSEQ){
      uint4 hv = *(const uint4*)(Acur + srow*AROWB + schunk*16);
      *(uint4*)(hbuf + ((size_t)(n0 + srow)*TT + (t - 1))*HH + schunk*8) = hv;
    }

    // acc init from LDS bias (opaque offset so loads are NOT hoisted to regs)
    int bo = w*32 + l15;
    asm("" : "+v"(bo));
    f32x4 acc[8];
    #pragma unroll
    for (int ct = 0; ct < 8; ++ct){
      float bv = lB[(ct >> 1)*256 + (ct & 1)*16 + bo];
      acc[ct] = (f32x4){bv, bv, bv, bv};
    }
    asm volatile("s_nop 1"
      : "+v"(acc[0]), "+v"(acc[1]), "+v"(acc[2]), "+v"(acc[3]),
        "+v"(acc[4]), "+v"(acc[5]), "+v"(acc[6]), "+v"(acc[7]));

    #define AFRAG(kt) (*(const v8bf*)(Acur + l15*AROWB + (kt)*64 + q*16))
    #define LFRAG(kt,ct) (*(const v8bf*)(lW + (((kt)-4)*8 + w)*4096 + (ct)*512 + lane*8))

    { v8bf a = AFRAG(6);                         // kt6 (loaded prev step) -> A<-kt8
      #pragma unroll
      for (int ct = 0; ct < 8; ++ct) mfma_v(acc[ct], a, sA[ct]);
      #pragma unroll
      for (int ct = 0; ct < 8; ++ct) sA[ct] = *(const v8bf*)(wpw + 8*SLABE + ct*512);
      __builtin_amdgcn_sched_barrier(0); }
    { v8bf a = AFRAG(0);                         // kt0..3 (AGPR) — widen kt8's gap
      #pragma unroll
      for (int ct = 0; ct < 8; ++ct) mfma_a(acc[ct], a, wreg[0][ct]); }
    { v8bf a = AFRAG(1);
      #pragma unroll
      for (int ct = 0; ct < 8; ++ct) mfma_a(acc[ct], a, wreg[1][ct]); }
    { v8bf a = AFRAG(2);
      #pragma unroll
      for (int ct = 0; ct < 8; ++ct) mfma_a(acc[ct], a, wreg[2][ct]); }
    { v8bf a = AFRAG(3);
      #pragma unroll
      for (int ct = 0; ct < 8; ++ct) mfma_a(acc[ct], a, wreg[3][ct]); }
    { v8bf a = AFRAG(7);                         // kt7 (loaded prev step) -> B<-kt9
      #pragma unroll
      for (int ct = 0; ct < 8; ++ct) mfma_v(acc[ct], a, sB[ct]);
      #pragma unroll
      for (int ct = 0; ct < 8; ++ct) sB[ct] = *(const v8bf*)(wpw + 9*SLABE + ct*512);
      __builtin_amdgcn_sched_barrier(0); }
    { v8bf a = AFRAG(4);                         // kt4 (LDS)
      #pragma unroll
      for (int ct = 0; ct < 8; ++ct) mfma_v(acc[ct], a, LFRAG(4,ct)); }
    { v8bf a = AFRAG(5);                         // kt5 (LDS)
      #pragma unroll
      for (int ct = 0; ct < 8; ++ct) mfma_v(acc[ct], a, LFRAG(5,ct)); }
    { v8bf a = AFRAG(8);                         // kt8 -> A<-kt6 for t+1
      #pragma unroll
      for (int ct = 0; ct < 8; ++ct) mfma_v(acc[ct], a, sA[ct]);
      #pragma unroll
      for (int ct = 0; ct < 8; ++ct) sA[ct] = *(const v8bf*)(wpw + 6*SLABE + ct*512);
      __builtin_amdgcn_sched_barrier(0); }
    { v8bf a = AFRAG(9);                         // kt9 -> B<-kt7 for t+1
      #pragma unroll
      for (int ct = 0; ct < 8; ++ct) mfma_v(acc[ct], a, sB[ct]);
      #pragma unroll
      for (int ct = 0; ct < 8; ++ct) sB[ct] = *(const v8bf*)(wpw + 7*SLABE + ct*512);
      __builtin_amdgcn_sched_barrier(0); }

    // MFMA->VALU hazard guard (asm MFMAs opaque to hazard recognizer)
    asm volatile("s_nop 7\n\ts_nop 7\n\ts_nop 7"
      : "+v"(acc[0]), "+v"(acc[1]), "+v"(acc[2]), "+v"(acc[3]),
        "+v"(acc[4]), "+v"(acc[5]), "+v"(acc[6]), "+v"(acc[7]));

    // elementwise cell update: lane owns units w*32+u*16+l15, rows 4q+j
    // (kt6'/kt7' loads for t+1 remain in flight under cell AND the soft barrier)
    #pragma unroll
    for (int u = 0; u < 2; ++u){
      #pragma unroll
      for (int j = 0; j < 4; ++j){
        float xi = acc[0 + u][j], xf = acc[2 + u][j], xg = acc[4 + u][j], xo = acc[6 + u][j];
        float cv = sigm(xf)*creg[u][j] + sigm(xi)*tanh_f(xg);
        float hv = sigm(xo)*tanh_f(cv);
        creg[u][j] = cv;
        int row = 4*q + j, unit = w*32 + u*16 + l15;
        *(u16*)(Anxt + row*AROWB + unit*2) = f2bf(hv);
      }
    }
    // stage y[t+1]
    if (t + 1 < TT)
      *(unsigned*)(Anxt + srow*AROWB + 512 + schunk*4) = yv;

    soft_barrier();   // LDS-visibility only: vmcnt NOT drained
  }
  { // final h[255] sits in buf (TT&1)=0
    char* Afin = lA + (TT & 1)*16*AROWB;
    if (n0 + srow < NSEQ){
      uint4 hv = *(const uint4*)(Afin + srow*AROWB + schunk*16);
      *(uint4*)(hbuf + ((size_t)(n0 + srow)*TT + (TT - 1))*HH + schunk*8) = hv;
    }
  }
}

// ---- out = h @ W_lin^T + b_lin, written as (B,OUT,F,T)
__global__ __launch_bounds__(256) void k_outproj(const u16* __restrict__ hbuf,
      const u16* __restrict__ wlin, const float* __restrict__ blin,
      float* __restrict__ out){
  extern __shared__ char smem[];
  u16* sA = (u16*)smem;                 // [128][264] rows = t
  u16* sB = (u16*)(smem + 128*264*2);   // [64][264]  rows = o
  const int n = blockIdx.x, th = blockIdx.y, t0 = th*128;
  const int b = n / 257, f = n % 257;
  const int tid = threadIdx.x, lane = tid & 63, wv = tid >> 6;

  for (int i = tid; i < 128*32; i += 256){
    int r = i >> 5, part = i & 31;
    *(uint4*)(sA + r*264 + part*8) =
        *(const uint4*)(hbuf + ((size_t)n*TT + t0 + r)*HH + part*8);
  }
  for (int i = tid; i < (64*264)/2; i += 256)
    ((unsigned*)sB)[i] = ((const unsigned*)wlin)[i];
  __syncthreads();

  f32x4 acc[2][4];
  #pragma unroll
  for (int m = 0; m < 2; ++m)
    #pragma unroll
    for (int nt = 0; nt < 4; ++nt){
      float bv = blin[nt*16 + (lane & 15)];
      acc[m][nt] = (f32x4){bv, bv, bv, bv};
    }
  const int khi = (lane >> 4) * 8;
  #pragma unroll
  for (int kt = 0; kt < 8; ++kt){
    v8bf av[2];
    #pragma unroll
    for (int m = 0; m < 2; ++m){
      int mt = wv*2 + m;
      av[m] = *(const v8bf*)(sA + (mt*16 + (lane & 15))*264 + kt*32 + khi);
    }
    #pragma unroll
    for (int nt = 0; nt < 4; ++nt){
      v8bf bv = *(const v8bf*)(sB + (nt*16 + (lane & 15))*264 + kt*32 + khi);
      #pragma unroll
      for (int m = 0; m < 2; ++m)
        acc[m][nt] = __builtin_amdgcn_mfma_f32_16x16x32_bf16(av[m], bv, acc[m][nt], 0, 0, 0);
    }
  }
  #pragma unroll
  for (int m = 0; m < 2; ++m){
    int mt = wv*2 + m;
    #pragma unroll
    for (int nt = 0; nt < 4; ++nt){
      int o = nt*16 + (lane & 15);
      int tb = t0 + mt*16 + 4*(lane >> 4);
      *(f32x4*)(out + (((size_t)b*64 + o)*257 + f)*TT + tb) = acc[m][nt];
    }
  }
}

extern "C" void kernel_launch(void* const* d_in, const int* in_sizes, int n_in,
                              void* d_out, int out_size, void* d_ws, size_t ws_size,
                              hipStream_t stream) {
  const float* x   = (const float*)d_in[0];
  const float* Wih = (const float*)d_in[1];
  const float* Whh = (const float*)d_in[2];
  const float* bih = (const float*)d_in[3];
  const float* bhh = (const float*)d_in[4];
  const float* Wl  = (const float*)d_in[5];
  const float* bl  = (const float*)d_in[6];
  float* out = (float*)d_out;

  char* p = (char*)d_ws;
  u16*   wpack = (u16*)p;   p += 655360;                 // 10 slabs
  float* bias  = (float*)p; p += 4096;
  u16*   wlin  = (u16*)p;   p += 33792;
  u16*   ybuf  = (u16*)p;   p += (size_t)NSEQ*TT*CC*2;   // 33.7 MB
  u16*   hbuf  = (u16*)p;                                // 134.7 MB

  hipFuncSetAttribute((const void*)k_lstm,    hipFuncAttributeMaxDynamicSharedMemorySize, LSTM_LDS);
  hipFuncSetAttribute((const void*)k_outproj, hipFuncAttributeMaxDynamicSharedMemorySize, OUTP_LDS);

  k_pack_w <<<1280, 256, 0, stream>>>(Whh, Wih, wpack);
  k_bias   <<<4,    256, 0, stream>>>(bih, bhh, bias);
  k_wlin   <<<66,   256, 0, stream>>>(Wl, wlin);
  k_ytrans <<<1028, 256, 0, stream>>>(x, ybuf);
  k_lstm   <<<65, 512, LSTM_LDS, stream>>>(wpack, bias, ybuf, hbuf);
  k_outproj<<<dim3(1028, 2), 256, OUTP_LDS, stream>>>(hbuf, wlin, bl, out);
}